// Round 18
// baseline (1466.481 us; speedup 1.0000x reference)
//
#include <hip/hip_runtime.h>
#include <hip/hip_bf16.h>

typedef unsigned short u16;
typedef __attribute__((ext_vector_type(8))) short bf16x8;
typedef __attribute__((ext_vector_type(4))) short bf16x4;
typedef __attribute__((ext_vector_type(4))) float f32x4;

typedef __attribute__((address_space(1))) const void gv_t;  // global
typedef __attribute__((address_space(3))) void lv_t;        // LDS

#define DEVINL __device__ __forceinline__

DEVINL float bf2f(u16 s) { union { unsigned u; float f; } v; v.u = ((unsigned)s) << 16; return v.f; }
DEVINL u16 f2bf(float f) {
  union { float f; unsigned u; } v; v.f = f;
  return (u16)((v.u + 0x7FFFu + ((v.u >> 16) & 1u)) >> 16);
}
DEVINL float elu_f(float v) { return v > 0.f ? v : __expf(v) - 1.f; }

// ---- ws probe ----
__global__ void probe_k(float* __restrict__ out, float v) { out[threadIdx.x] = v; }

// ---- batched layer-2 packs (g1-scaled): 5 jobs x 1024 blocks ----
struct PackPtrs { const float* wl2; const float* wr2; const float* g1; u16* bt[5]; };
__global__ __launch_bounds__(256) void pack_multi(PackPtrs p) {
  int j = blockIdx.x >> 10;
  int idx = (blockIdx.x & 1023) * 256 + threadIdx.x;
  int k = idx >> 9, n = idx & 511;
  float v;
  if (j < 4) {
    int r = (j == 3) ? 4 : j;
    v = p.wl2[((size_t)r * 512 + k) * 512 + n];
  } else {
    size_t o = (size_t)k * 512 + n;
    v = p.wr2[o] + p.wr2[o + 262144] + p.wr2[o + 524288] + p.wr2[o + 1048576];
  }
  p.bt[j][(size_t)n * 512 + k] = f2bf(v * 0.25f * p.g1[k]);
}

// ---- per-matrix LN-fold constants ----
__global__ __launch_bounds__(256) void csbb_k(const float* __restrict__ wl2,
                                              const float* __restrict__ wr2,
                                              const float* __restrict__ g1,
                                              const float* __restrict__ be1,
                                              float* __restrict__ cs, float* __restrict__ bb) {
  __shared__ float redA[256], redB[256];
  int j = blockIdx.x >> 4;
  int n = (blockIdx.x & 15) * 32 + (threadIdx.x & 31);
  int kg = threadIdx.x >> 5;
  float a = 0.f, b = 0.f;
  for (int k = kg * 64; k < kg * 64 + 64; ++k) {
    float w;
    if (j < 4) {
      int r = (j == 3) ? 4 : j;
      w = wl2[((size_t)r * 512 + k) * 512 + n];
    } else {
      size_t o = (size_t)k * 512 + n;
      w = wr2[o] + wr2[o + 262144] + wr2[o + 524288] + wr2[o + 1048576];
    }
    a += g1[k] * w;
    b += be1[k] * w;
  }
  redA[threadIdx.x] = a;
  redB[threadIdx.x] = b;
  __syncthreads();
  if (kg == 0) {
    float va = 0.f, vb = 0.f;
#pragma unroll
    for (int q = 0; q < 8; ++q) {
      va += redA[(threadIdx.x & 31) + q * 32];
      vb += redB[(threadIdx.x & 31) + q * 32];
    }
    cs[j * 512 + n] = va * 0.25f;
    bb[j * 512 + n] = vb * 0.25f;
  }
}

// ================= batched layer-1 weight folding (18 jobs) =================
struct FoldPtrs { const float* a[8]; const float* w[2]; u16* bt[4]; };
__constant__ int   c_off[19] = {0,16,24,56,64,320,328,360,368,400,416,424,440,696,704,960,1216,1224,1256};
__constant__ int   c_ai[18]  = {0,1,2,3,4,5,6,7,6, 0,1,0, 4,5,4, 4,5,2};
__constant__ int   c_wi[18]  = {0,0,0,0,0,0,0,0,1, 0,0,1, 0,0,1, 0,0,1};
__constant__ int   c_r0[18]  = {0,0,1,1,2,2,4,4,0, 5,5,5, 6,6,6, 3,3,3};
__constant__ float c_sc[18]  = {0.25f,0.25f,0.25f,0.25f,0.25f,0.25f,0.25f,0.25f,0.25f,
                                1.f,1.f,1.f, 1.f,1.f,1.f, 1.f,1.f,1.f};
__constant__ int   c_bt[18]  = {0,0,0,0,0,0,0,0,0, 1,1,1, 2,2,2, 3,3,3};
__constant__ int   c_K[18]   = {64,64,64,64,64,64,64,64,64, 64,64,64, 128,128,128, 64,64,64};
__constant__ int   c_ko[18]  = {0,2,3,7,8,40,41,45,46, 0,2,3, 0,32,33, 0,32,33};

__global__ __launch_bounds__(256) void fold_multi(FoldPtrs p) {
  __shared__ float red[256];
  int b = blockIdx.x;
  int j = 0;
#pragma unroll
  for (int t = 1; t < 18; ++t) j += (b >= c_off[t]);
  int rel = b - c_off[j];
  int f = rel >> 3, nb = rel & 7;
  int tid = threadIdx.x;
  int n = nb * 64 + (tid & 63);
  int kg = tid >> 6;
  const float* A = p.a[c_ai[j]] + (size_t)f * 512;
  const float* W = p.w[c_wi[j]];
  int k0 = kg * 128;
  float acc = 0.f;
  if (j != 8) {
    const float* Wp = W + (size_t)c_r0[j] * 512 * 512 + n;
#pragma unroll 16
    for (int k = k0; k < k0 + 128; ++k) acc += A[k] * Wp[(size_t)k * 512];
  } else {
    const float* W0 = W + n;
    const float* W1 = W + (size_t)262144 + n;
    const float* W2 = W + (size_t)524288 + n;
    const float* W4 = W + (size_t)1048576 + n;
#pragma unroll 8
    for (int k = k0; k < k0 + 128; ++k) {
      size_t o = (size_t)k * 512;
      acc += A[k] * (W0[o] + W1[o] + W2[o] + W4[o]);
    }
  }
  red[tid] = acc;
  __syncthreads();
  if (kg == 0) {
    float v = red[tid] + red[tid + 64] + red[tid + 128] + red[tid + 192];
    p.bt[c_bt[j]][(size_t)n * c_K[j] + c_ko[j] + f] = f2bf(v * c_sc[j]);
  }
}

// ---- batched bias folds ----
struct VFPtrs { const float* bl[5]; const float* bvec[5]; const float* w; float* out[5]; };
__constant__ int   c_vi[5][4] = {{0,1,2,4},{0,1,2,4},{5,-1,-1,-1},{6,-1,-1,-1},{3,-1,-1,-1}};
__constant__ float c_vs[5]    = {0.25f,0.25f,1.f,1.f,1.f};

__global__ __launch_bounds__(256) void vecfold_multi(VFPtrs p) {
  __shared__ float red[256];
  int j = blockIdx.x >> 4, blk = blockIdx.x & 15;
  int tid = threadIdx.x;
  int n = blk * 32 + (tid & 31);
  int kg = tid >> 5;
  const float* bv = p.bvec[j];
  float a = 0.f;
  if (bv) {
    int i1 = c_vi[j][1];
    const float* W0 = p.w + (size_t)c_vi[j][0] * 262144 + n;
    if (i1 < 0) {
#pragma unroll 16
      for (int k = kg * 64; k < kg * 64 + 64; ++k) a += bv[k] * W0[(size_t)k * 512];
    } else {
      const float* W1 = p.w + (size_t)c_vi[j][1] * 262144 + n;
      const float* W2 = p.w + (size_t)c_vi[j][2] * 262144 + n;
      const float* W3 = p.w + (size_t)c_vi[j][3] * 262144 + n;
#pragma unroll 8
      for (int k = kg * 64; k < kg * 64 + 64; ++k) {
        size_t o = (size_t)k * 512;
        a += bv[k] * (W0[o] + W1[o] + W2[o] + W3[o]);
      }
    }
  }
  red[tid] = a;
  __syncthreads();
  if (kg == 0) {
    float v = 0.f;
#pragma unroll
    for (int q = 0; q < 8; ++q) v += red[(tid & 31) + q * 32];
    float bsum = p.bl[j][c_vi[j][0] * 512 + n];
    if (c_vi[j][1] >= 0) {
      bsum += p.bl[j][c_vi[j][1] * 512 + n];
      bsum += p.bl[j][c_vi[j][2] * 512 + n];
      bsum += p.bl[j][c_vi[j][3] * 512 + n];
    }
    p.out[j][n] = (v + bsum) * c_vs[j];
  }
}

// ================= CSR build: XCD-range-partitioned atomics =================
struct EdgePtrs { const int* dst[7]; const int* src[7]; };
__constant__ int c_hoff[8]  = {0,1024,2048,3072,4096,5120,5248,5760};
__constant__ int c_hbase[7] = {0,131072,262144,393216,458752,589824,622592};
__constant__ int c_hne[7]   = {262144,262144,262144,262144,262144,32768,131072};

__global__ __launch_bounds__(256) void hist8(EdgePtrs p, int* __restrict__ cnt) {
  int range = blockIdx.x & 7;
  int lo = range * 94208, hi = lo + 94208;
  for (int chunk = blockIdx.x >> 3; chunk < 5760; chunk += 4096) {
    int j = 0;
#pragma unroll
    for (int t = 1; t < 7; ++t) j += (chunk >= c_hoff[t]);
    int i = (chunk - c_hoff[j]) * 256 + threadIdx.x;
    if (i < c_hne[j]) {
      int idx = c_hbase[j] + p.dst[j][i];
      if (idx >= lo && idx < hi) atomicAdd(&cnt[idx], 1);
    }
  }
}

__global__ __launch_bounds__(256) void fill8(EdgePtrs p, int* __restrict__ cursor,
                                             int* __restrict__ esrc) {
  int range = blockIdx.x & 7;
  int lo = range * 94208, hi = lo + 94208;
  for (int chunk = blockIdx.x >> 3; chunk < 5760; chunk += 4096) {
    int j = 0;
#pragma unroll
    for (int t = 1; t < 7; ++t) j += (chunk >= c_hoff[t]);
    int i = (chunk - c_hoff[j]) * 256 + threadIdx.x;
    if (i < c_hne[j]) {
      int idx = c_hbase[j] + p.dst[j][i];
      if (idx >= lo && idx < hi) {
        int pos = atomicAdd(&cursor[idx], 1);
        esrc[pos] = p.src[j][i];
      }
    }
  }
}

__global__ void scan1_k(const int* __restrict__ in, int* __restrict__ out,
                        int* __restrict__ part, int n) {
  __shared__ int s[256];
  int t = threadIdx.x;
  int base = blockIdx.x * 1024 + t * 4;
  int x0 = 0, x1 = 0, x2 = 0, x3 = 0;
  if (base < n) x0 = in[base];
  if (base + 1 < n) x1 = in[base + 1];
  if (base + 2 < n) x2 = in[base + 2];
  if (base + 3 < n) x3 = in[base + 3];
  int tsum = x0 + x1 + x2 + x3;
  s[t] = tsum;
  __syncthreads();
  for (int off = 1; off < 256; off <<= 1) {
    int v = (t >= off) ? s[t - off] : 0;
    __syncthreads();
    s[t] += v;
    __syncthreads();
  }
  int excl = s[t] - tsum;
  if (base < n) out[base] = excl;
  if (base + 1 < n) out[base + 1] = excl + x0;
  if (base + 2 < n) out[base + 2] = excl + x0 + x1;
  if (base + 3 < n) out[base + 3] = excl + x0 + x1 + x2;
  if (t == 255) part[blockIdx.x] = s[255];
}

__global__ void scan2_k(int* __restrict__ part, int nb) {
  __shared__ int s[1024];
  int t = threadIdx.x;
  int orig = (t < nb) ? part[t] : 0;
  s[t] = orig;
  __syncthreads();
  for (int off = 1; off < 1024; off <<= 1) {
    int v = (t >= off) ? s[t - off] : 0;
    __syncthreads();
    s[t] += v;
    __syncthreads();
  }
  if (t < nb) part[t] = s[t] - orig;
}

__global__ void scan3_k(int* __restrict__ out, int* __restrict__ cursor,
                        const int* __restrict__ part, int n) {
  int i = blockIdx.x * 256 + threadIdx.x;
  if (i < n) {
    int v = out[i] + part[i >> 10];
    out[i] = v;
    cursor[i] = v;
  }
}

// ---- raw-feature segment mean + indicator (8 threads per dst row) ----
__global__ void raw_agg(const int* __restrict__ offs, const int* __restrict__ esrc,
                        const float* __restrict__ x, int F, u16* __restrict__ A1,
                        int K, int colOff, int indCol, int nd) {
  int row = blockIdx.x * 32 + (threadIdx.x >> 3);
  if (row >= nd) return;
  int j = threadIdx.x & 7;
  int e0 = offs[row], e1 = offs[row + 1];
  float acc[4] = {0.f, 0.f, 0.f, 0.f};
  for (int e = e0; e < e1; ++e) {
    int s = esrc[e];
#pragma unroll
    for (int u = 0; u < 4; ++u) {
      int f = j + u * 8;
      if (f < F) acc[u] += x[(size_t)s * F + f];
    }
  }
  float inv = (e1 > e0) ? 1.f / (float)(e1 - e0) : 0.f;
#pragma unroll
  for (int u = 0; u < 4; ++u) {
    int f = j + u * 8;
    if (f < F) A1[(size_t)row * K + colOff + f] = f2bf(acc[u] * inv);
  }
  if (j == 0) A1[(size_t)row * K + indCol] = f2bf((e1 > e0) ? 1.f : 0.f);
}

// batched op-stage: 4 jobs x 1024 blocks, K=64, 32768 rows/chunk
struct RawPtrs { const int* offs; const int* esrc; const float* x[4]; u16* A1; };
__constant__ int c_gF[4]    = {2,4,32,4};
__constant__ int c_gco[4]   = {0,3,8,41};
__constant__ int c_gic[4]   = {2,7,40,45};
__constant__ int c_gcsrb[4] = {0,131072,262144,458752};

__global__ __launch_bounds__(256) void raw_multi(RawPtrs p, int s0) {
  int j = blockIdx.x >> 10;
  int row = (blockIdx.x & 1023) * 32 + (threadIdx.x >> 3);
  int jj = threadIdx.x & 7;
  const int* offs = p.offs + c_gcsrb[j] + s0;
  const float* x = p.x[j];
  int F = c_gF[j];
  int e0 = offs[row], e1 = offs[row + 1];
  float acc[4] = {0.f, 0.f, 0.f, 0.f};
  for (int e = e0; e < e1; ++e) {
    int s = p.esrc[e];
#pragma unroll
    for (int u = 0; u < 4; ++u) {
      int f = jj + u * 8;
      if (f < F) acc[u] += x[(size_t)s * F + f];
    }
  }
  float inv = (e1 > e0) ? 1.f / (float)(e1 - e0) : 0.f;
#pragma unroll
  for (int u = 0; u < 4; ++u) {
    int f = jj + u * 8;
    if (f < F) p.A1[(size_t)row * 64 + c_gco[j] + f] = f2bf(acc[u] * inv);
  }
  if (jj == 0) p.A1[(size_t)row * 64 + c_gic[j]] = f2bf((e1 > e0) ? 1.f : 0.f);
}

// ---- copy root raw features into A1 ----
__global__ void a1_root(const float* __restrict__ x, int rowBase, u16* __restrict__ A1,
                        int K, int rootOff, int nd, int lf) {
  int idx = blockIdx.x * 256 + threadIdx.x;
  int i = idx >> lf, f = idx & ((1 << lf) - 1);
  if (i >= nd) return;
  A1[(size_t)i * K + rootOff + f] = f2bf(x[(((size_t)(rowBase + i)) << lf) + f]);
}

// ---- fused gather + acc RMW: 4 dst rows per wave (4x memory-level parallelism) ----
template <bool FIRST>
__global__ __launch_bounds__(256) void gather_acc(
    const int* __restrict__ offs, const int* __restrict__ esrc,
    const u16* __restrict__ hT, const float* __restrict__ bias,
    u16* __restrict__ acc, int s0, int s1) {
  int w0 = (blockIdx.x * 4 + (threadIdx.x >> 6)) * 4;  // rows w0..w0+3
  int l = threadIdx.x & 63;
  int o0 = offs[w0], o1 = offs[w0 + 1], o2 = offs[w0 + 2], o3 = offs[w0 + 3], o4 = offs[w0 + 4];
  int len[4] = {o1 - o0, o2 - o1, o3 - o2, o4 - o3};
  int base[4] = {o0, o1, o2, o3};
  int maxLen = len[0];
#pragma unroll
  for (int r = 1; r < 4; ++r) maxLen = len[r] > maxLen ? len[r] : maxLen;
  float sum[4][8];
#pragma unroll
  for (int r = 0; r < 4; ++r)
#pragma unroll
    for (int j = 0; j < 8; ++j) sum[r][j] = 0.f;
  bool found[4] = {false, false, false, false};
  for (int i = 0; i < maxLen; ++i) {
    int s[4];
    bool d[4];
#pragma unroll
    for (int r = 0; r < 4; ++r) {
      s[r] = (i < len[r]) ? esrc[base[r] + i] : -1;
      d[r] = (s[r] >= s0 && s[r] < s1);
    }
    bf16x8 v[4];
#pragma unroll
    for (int r = 0; r < 4; ++r)
      if (d[r]) v[r] = *(const bf16x8*)&hT[(size_t)(s[r] - s0) * 512 + l * 8];
#pragma unroll
    for (int r = 0; r < 4; ++r)
      if (d[r]) {
        found[r] = true;
#pragma unroll
        for (int j = 0; j < 8; ++j) sum[r][j] += bf2f((u16)v[r][j]);
      }
  }
#pragma unroll
  for (int r = 0; r < 4; ++r) {
    float inv = (len[r] > 0) ? 1.f / (float)len[r] : 0.f;
    u16* ap = acc + (size_t)(w0 + r) * 512 + l * 8;
    bf16x8 res;
    if (FIRST) {
#pragma unroll
      for (int j = 0; j < 8; ++j) res[j] = (short)f2bf(bias[l * 8 + j] + sum[r][j] * inv);
      *(bf16x8*)ap = res;
    } else if (found[r]) {
      bf16x8 old = *(const bf16x8*)ap;
#pragma unroll
      for (int j = 0; j < 8; ++j) res[j] = (short)f2bf(bf2f((u16)old[j]) + sum[r][j] * inv);
      *(bf16x8*)ap = res;
    }
  }
}

// ---- MFMA GEMM (layer-1, K=64/128, M=32768): XCD-swizzled flat grid 1024 ----
template <bool ELU, int K>
__global__ __launch_bounds__(256) void gemm_k(
    const u16* __restrict__ A, const u16* __restrict__ BT,
    const float* __restrict__ bias, u16* __restrict__ C) {
  __shared__ u16 As[128 * 64];
  __shared__ u16 Bs[128 * 64];
  int b = blockIdx.x;
  int u = (b & 7) * 128 + (b >> 3);
  int bm = (u >> 2) * 128;
  int bn = (u & 3) * 128;
  int tid = threadIdx.x;
  int wid = tid >> 6, lane = tid & 63;
  int wm = wid >> 1, wn = wid & 1;
  int r16 = lane & 15, hi4 = lane >> 4;
  int srow = tid >> 3;
  int scol = ((tid & 7) ^ (srow & 7)) * 8;
  int sw = r16 & 7;
  f32x4 acc[4][4];
#pragma unroll
  for (int i = 0; i < 4; ++i)
#pragma unroll
    for (int j = 0; j < 4; ++j) acc[i][j] = (f32x4){0.f, 0.f, 0.f, 0.f};

#pragma unroll
  for (int k0 = 0; k0 < K; k0 += 64) {
    __syncthreads();
#pragma unroll
    for (int i = 0; i < 4; ++i) {
      const u16* ga = A + (size_t)(bm + i * 32 + srow) * K + k0 + scol;
      const u16* gb = BT + (size_t)(bn + i * 32 + srow) * K + k0 + scol;
      __builtin_amdgcn_global_load_lds((gv_t*)ga, (lv_t*)(As + i * 2048 + wid * 512), 16, 0, 0);
      __builtin_amdgcn_global_load_lds((gv_t*)gb, (lv_t*)(Bs + i * 2048 + wid * 512), 16, 0, 0);
    }
    __syncthreads();
#pragma unroll
    for (int kk = 0; kk < 64; kk += 32) {
      bf16x8 af[4], bfr[4];
#pragma unroll
      for (int f = 0; f < 4; ++f) {
        int grp = (kk >> 3) + hi4;
        af[f]  = *(const bf16x8*)&As[(wm * 64 + f * 16 + r16) * 64 + ((grp ^ sw) << 3)];
        bfr[f] = *(const bf16x8*)&Bs[(wn * 64 + f * 16 + r16) * 64 + ((grp ^ sw) << 3)];
      }
#pragma unroll
      for (int mf = 0; mf < 4; ++mf)
#pragma unroll
        for (int nf = 0; nf < 4; ++nf)
          acc[mf][nf] = __builtin_amdgcn_mfma_f32_16x16x32_bf16(bfr[nf], af[mf], acc[mf][nf], 0, 0, 0);
    }
  }
#pragma unroll
  for (int mf = 0; mf < 4; ++mf) {
    int r = bm + wm * 64 + mf * 16 + r16;
#pragma unroll
    for (int nf = 0; nf < 4; ++nf) {
      int c0 = bn + wn * 64 + nf * 16 + hi4 * 4;
      u16* cp = C + (size_t)r * 512 + c0;
      f32x4 bv = *(const f32x4*)&bias[c0];
      bf16x4 res;
#pragma unroll
      for (int j = 0; j < 4; ++j) {
        float v = acc[mf][nf][j] + bv[j];
        if (ELU) v = elu_f(v);
        res[j] = (short)f2bf(v);
      }
      *(bf16x4*)cp = res;
    }
  }
}

// ---- per-row LN stats of h1 (wave per row) ----
__global__ void ln_stats(const u16* __restrict__ H, float2* __restrict__ stats, int rows) {
  int w = blockIdx.x * 4 + (threadIdx.x >> 6);
  if (w >= rows) return;
  int l = threadIdx.x & 63;
  bf16x8 v = *(const bf16x8*)&H[(size_t)w * 512 + l * 8];
  float x[8];
  float s = 0.f;
#pragma unroll
  for (int j = 0; j < 8; ++j) { x[j] = bf2f((u16)v[j]); s += x[j]; }
#pragma unroll
  for (int m = 1; m < 64; m <<= 1) s += __shfl_xor(s, m, 64);
  float mean = s * (1.f / 512.f);
  float q = 0.f;
#pragma unroll
  for (int j = 0; j < 8; ++j) { float d = x[j] - mean; q += d * d; }
#pragma unroll
  for (int m = 1; m < 64; m <<= 1) q += __shfl_xor(q, m, 64);
  if (l == 0) stats[w] = make_float2(mean, rsqrtf(q * (1.f / 512.f) + 1e-5f));
}

// ---- transform GEMM (K=512) with fused LN-of-A; XCD-chunked swizzle ----
template <bool ACC>
__global__ __launch_bounds__(256) void gemm_t(
    const u16* __restrict__ A, const u16* __restrict__ BT, u16* __restrict__ C,
    const float2* __restrict__ stats, const float* __restrict__ cs,
    const float* __restrict__ bb) {
  __shared__ u16 As[128 * 64];
  __shared__ u16 Bs[128 * 64];
  int b = blockIdx.x;
  int u = (b & 7) * 128 + (b >> 3);
  int bm = (u >> 2) * 128;
  int bn = (u & 3) * 128;
  int tid = threadIdx.x;
  int wid = tid >> 6, lane = tid & 63;
  int wm = wid >> 1, wn = wid & 1;
  int r16 = lane & 15, hi4 = lane >> 4;
  int srow = tid >> 3;
  int scol = ((tid & 7) ^ (srow & 7)) * 8;
  int sw = r16 & 7;
  f32x4 acc[4][4];
#pragma unroll
  for (int i = 0; i < 4; ++i)
#pragma unroll
    for (int j = 0; j < 4; ++j) acc[i][j] = (f32x4){0.f, 0.f, 0.f, 0.f};

#pragma unroll
  for (int k0 = 0; k0 < 512; k0 += 64) {
    __syncthreads();
#pragma unroll
    for (int i = 0; i < 4; ++i) {
      const u16* ga = A + (size_t)(bm + i * 32 + srow) * 512 + k0 + scol;
      const u16* gb = BT + (size_t)(bn + i * 32 + srow) * 512 + k0 + scol;
      __builtin_amdgcn_global_load_lds((gv_t*)ga, (lv_t*)(As + i * 2048 + wid * 512), 16, 0, 0);
      __builtin_amdgcn_global_load_lds((gv_t*)gb, (lv_t*)(Bs + i * 2048 + wid * 512), 16, 0, 0);
    }
    __syncthreads();
#pragma unroll
    for (int kk = 0; kk < 64; kk += 32) {
      bf16x8 af[4], bfr[4];
#pragma unroll
      for (int f = 0; f < 4; ++f) {
        int grp = (kk >> 3) + hi4;
        af[f]  = *(const bf16x8*)&As[(wm * 64 + f * 16 + r16) * 64 + ((grp ^ sw) << 3)];
        bfr[f] = *(const bf16x8*)&Bs[(wn * 64 + f * 16 + r16) * 64 + ((grp ^ sw) << 3)];
      }
#pragma unroll
      for (int mf = 0; mf < 4; ++mf)
#pragma unroll
        for (int nf = 0; nf < 4; ++nf)
          acc[mf][nf] = __builtin_amdgcn_mfma_f32_16x16x32_bf16(bfr[nf], af[mf], acc[mf][nf], 0, 0, 0);
    }
  }
#pragma unroll
  for (int mf = 0; mf < 4; ++mf) {
    int r = bm + wm * 64 + mf * 16 + r16;
    float2 st = stats[r];
    float mr = st.x * st.y;
#pragma unroll
    for (int nf = 0; nf < 4; ++nf) {
      int c0 = bn + wn * 64 + nf * 16 + hi4 * 4;
      u16* cp = C + (size_t)r * 512 + c0;
      f32x4 csv = *(const f32x4*)&cs[c0];
      f32x4 bbv = *(const f32x4*)&bb[c0];
      bf16x4 res;
      if (ACC) {
        bf16x4 oldv = *(const bf16x4*)cp;
#pragma unroll
        for (int j = 0; j < 4; ++j) {
          float v = st.y * acc[mf][nf][j] - mr * csv[j] + bbv[j] + bf2f((u16)oldv[j]);
          res[j] = (short)f2bf(v);
        }
      } else {
#pragma unroll
        for (int j = 0; j < 4; ++j) {
          float v = st.y * acc[mf][nf][j] - mr * csv[j] + bbv[j];
          res[j] = (short)f2bf(v);
        }
      }
      *(bf16x4*)cp = res;
    }
  }
}

// ---- dual transform for stage F ----
__global__ __launch_bounds__(256) void gemm_t2(
    const u16* __restrict__ A, const u16* __restrict__ BTrt, const u16* __restrict__ BT4,
    u16* __restrict__ Cacc, u16* __restrict__ ChT, const float2* __restrict__ stats,
    const float* __restrict__ csrt, const float* __restrict__ bbrt,
    const float* __restrict__ cs4, const float* __restrict__ bb4) {
  __shared__ u16 As[128 * 64];
  __shared__ u16 Bs[128 * 64];
  bool second = blockIdx.x >= 1024;
  const u16* BT = second ? BT4 : BTrt;
  u16* C = second ? ChT : Cacc;
  const float* cs = second ? cs4 : csrt;
  const float* bb = second ? bb4 : bbrt;
  int b = blockIdx.x & 1023;
  int u = (b & 7) * 128 + (b >> 3);
  int bm = (u >> 2) * 128;
  int bn = (u & 3) * 128;
  int tid = threadIdx.x;
  int wid = tid >> 6, lane = tid & 63;
  int wm = wid >> 1, wn = wid & 1;
  int r16 = lane & 15, hi4 = lane >> 4;
  int srow = tid >> 3;
  int scol = ((tid & 7) ^ (srow & 7)) * 8;
  int sw = r16 & 7;
  f32x4 acc[4][4];
#pragma unroll
  for (int i = 0; i < 4; ++i)
#pragma unroll
    for (int j = 0; j < 4; ++j) acc[i][j] = (f32x4){0.f, 0.f, 0.f, 0.f};

#pragma unroll
  for (int k0 = 0; k0 < 512; k0 += 64) {
    __syncthreads();
#pragma unroll
    for (int i = 0; i < 4; ++i) {
      const u16* ga = A + (size_t)(bm + i * 32 + srow) * 512 + k0 + scol;
      const u16* gb = BT + (size_t)(bn + i * 32 + srow) * 512 + k0 + scol;
      __builtin_amdgcn_global_load_lds((gv_t*)ga, (lv_t*)(As + i * 2048 + wid * 512), 16, 0, 0);
      __builtin_amdgcn_global_load_lds((gv_t*)gb, (lv_t*)(Bs + i * 2048 + wid * 512), 16, 0, 0);
    }
    __syncthreads();
#pragma unroll
    for (int kk = 0; kk < 64; kk += 32) {
      bf16x8 af[4], bfr[4];
#pragma unroll
      for (int f = 0; f < 4; ++f) {
        int grp = (kk >> 3) + hi4;
        af[f]  = *(const bf16x8*)&As[(wm * 64 + f * 16 + r16) * 64 + ((grp ^ sw) << 3)];
        bfr[f] = *(const bf16x8*)&Bs[(wn * 64 + f * 16 + r16) * 64 + ((grp ^ sw) << 3)];
      }
#pragma unroll
      for (int mf = 0; mf < 4; ++mf)
#pragma unroll
        for (int nf = 0; nf < 4; ++nf)
          acc[mf][nf] = __builtin_amdgcn_mfma_f32_16x16x32_bf16(bfr[nf], af[mf], acc[mf][nf], 0, 0, 0);
    }
  }
#pragma unroll
  for (int mf = 0; mf < 4; ++mf) {
    int r = bm + wm * 64 + mf * 16 + r16;
    float2 st = stats[r];
    float mr = st.x * st.y;
#pragma unroll
    for (int nf = 0; nf < 4; ++nf) {
      int c0 = bn + wn * 64 + nf * 16 + hi4 * 4;
      u16* cp = C + (size_t)r * 512 + c0;
      f32x4 csv = *(const f32x4*)&cs[c0];
      f32x4 bbv = *(const f32x4*)&bb[c0];
      bf16x4 res;
      if (!second) {
        bf16x4 oldv = *(const bf16x4*)cp;
#pragma unroll
        for (int j = 0; j < 4; ++j) {
          float v = st.y * acc[mf][nf][j] - mr * csv[j] + bbv[j] + bf2f((u16)oldv[j]);
          res[j] = (short)f2bf(v);
        }
      } else {
#pragma unroll
        for (int j = 0; j < 4; ++j) {
          float v = st.y * acc[mf][nf][j] - mr * csv[j] + bbv[j];
          res[j] = (short)f2bf(v);
        }
      }
      *(bf16x4*)cp = res;
    }
  }
}

// ---- fused ELU + LN2 + pool partial (16 parts/graph, NO atomics) ----
DEVINL int lowb(const int* a, int n, int v) {
  int lo = 0, hi = n;
  while (lo < hi) { int m = (lo + hi) >> 1; if (a[m] < v) lo = m + 1; else hi = m; }
  return lo;
}

__global__ __launch_bounds__(256) void pool1v(const u16* __restrict__ H,
                                              const int* __restrict__ batch, int nOp,
                                              const float* __restrict__ g2,
                                              const float* __restrict__ be2,
                                              float* __restrict__ poolp,
                                              int* __restrict__ cnts) {
  __shared__ float red[4][512];
  int gr = blockIdx.x >> 4, part = blockIdx.x & 15;
  int lo = lowb(batch, nOp, gr), hi = lowb(batch, nOp, gr + 1);
  if (part == 0 && threadIdx.x == 0) cnts[gr] = hi - lo;
  int len = hi - lo;
  int chunk = (len + 15) >> 4;
  int r0 = lo + part * chunk;
  int r1 = r0 + chunk;
  if (r1 > hi) r1 = hi;
  int wv = threadIdx.x >> 6, l = threadIdx.x & 63;
  float a[8] = {0.f, 0.f, 0.f, 0.f, 0.f, 0.f, 0.f, 0.f};
  float gv[8], bv[8];
#pragma unroll
  for (int j = 0; j < 8; ++j) { gv[j] = g2[l * 8 + j]; bv[j] = be2[l * 8 + j]; }
  for (int r = r0 + wv; r < r1; r += 4) {
    bf16x8 v = *(const bf16x8*)&H[(size_t)r * 512 + l * 8];
    float x[8];
    float s = 0.f;
#pragma unroll
    for (int j = 0; j < 8; ++j) {
      x[j] = elu_f(bf2f((u16)v[j]));
      s += x[j];
    }
#pragma unroll
    for (int m = 1; m < 64; m <<= 1) s += __shfl_xor(s, m, 64);
    float mean = s * (1.f / 512.f);
    float q = 0.f;
#pragma unroll
    for (int j = 0; j < 8; ++j) { float d = x[j] - mean; q += d * d; }
#pragma unroll
    for (int m = 1; m < 64; m <<= 1) q += __shfl_xor(q, m, 64);
    float rsd = rsqrtf(q * (1.f / 512.f) + 1e-5f);
#pragma unroll
    for (int j = 0; j < 8; ++j) a[j] += (x[j] - mean) * rsd * gv[j] + bv[j];
  }
#pragma unroll
  for (int j = 0; j < 8; ++j) red[wv][l * 8 + j] = a[j];
  __syncthreads();
  if (wv == 0) {
    float* dst = poolp + (size_t)blockIdx.x * 512;
#pragma unroll
    for (int j = 0; j < 8; ++j) {
      int c = l * 8 + j;
      dst[c] = red[0][c] + red[1][c] + red[2][c] + red[3][c];
    }
  }
}

__global__ void pool2(const float* __restrict__ poolp, const int* __restrict__ cnts,
                      const float* __restrict__ Wout, const float* __restrict__ bout,
                      float* __restrict__ out) {
  int gg = blockIdx.x;
  int l = threadIdx.x;
  float s = 0.f;
#pragma unroll
  for (int j = 0; j < 8; ++j) {
    int c = l * 8 + j;
    float t = 0.f;
#pragma unroll
    for (int p = 0; p < 16; ++p) t += poolp[(size_t)(gg * 16 + p) * 512 + c];
    s += t * Wout[c];
  }
#pragma unroll
  for (int m = 1; m < 64; m <<= 1) s += __shfl_xor(s, m, 64);
  if (l == 0) {
    int c = cnts[gg];
    if (c < 1) c = 1;
    out[gg] = s / (float)c + bout[0];
  }
}

extern "C" void kernel_launch(void* const* d_in, const int* in_sizes, int n_in,
                              void* d_out, int out_size, void* d_ws, size_t ws_size,
                              hipStream_t stream) {
  (void)in_sizes; (void)n_in; (void)out_size;
  const float* x_op   = (const float*)d_in[0];
  const float* x_tab  = (const float*)d_in[1];
  const float* x_col  = (const float*)d_in[2];
  const float* x_pred = (const float*)d_in[3];
  const float* W_op = (const float*)d_in[4],  *b_op = (const float*)d_in[5];
  const float* W_tab = (const float*)d_in[6], *b_tab = (const float*)d_in[7];
  const float* W_col = (const float*)d_in[8], *b_col = (const float*)d_in[9];
  const float* W_pred = (const float*)d_in[10], *b_pred = (const float*)d_in[11];
  const float* Wl1 = (const float*)d_in[12];
  const float* bl1 = (const float*)d_in[13];
  const float* Wr1 = (const float*)d_in[14];
  const float* Wl2 = (const float*)d_in[15];
  const float* bl2 = (const float*)d_in[16];
  const float* Wr2 = (const float*)d_in[17];
  const float* g1  = (const float*)d_in[18];
  const float* be1 = (const float*)d_in[19];
  const float* g2  = (const float*)d_in[20];
  const float* be2 = (const float*)d_in[21];
  const float* Wout = (const float*)d_in[22];
  const float* bout = (const float*)d_in[23];
  const int* SRC[7], *DST[7];
  for (int r = 0; r < 7; ++r) { SRC[r] = (const int*)d_in[24 + 2 * r]; DST[r] = (const int*)d_in[25 + 2 * r]; }
  const int* batch = (const int*)d_in[38];
  float* out = (float*)d_out;

  const int CSRB[7] = {0, 131072, 262144, 393216, 458752, 589824, 622592};
  const int TOT = 753664;
  const int NOP = 131072;

  // ---- workspace layout ----
  char* ws = (char*)d_ws;
  u16* acc     = (u16*)ws;                          // 134,217,728
  u16* h1      = (u16*)(ws + 134217728ull);         //  33,554,432
  int* curFul  = (int*)(ws + 134217728ull);         //   (overlay)
  u16* hT      = (u16*)(ws + 167772160ull);         //  67,108,864
  u16* A1      = (u16*)(ws + 234881024ull);         //   8,388,608
  int* offsFul = (int*)(ws + 243269632ull);         //   3,014,912
  int* esrcFul = (int*)(ws + 246284544ull);         //   5,898,240
  u16* BT2_0   = (u16*)(ws + 252182784ull);         //   5 x 524,288
  u16* BT2_1   = BT2_0 + 262144;
  u16* BT2_2   = BT2_1 + 262144;
  u16* BT2_4   = BT2_2 + 262144;
  u16* BT2rt   = BT2_4 + 262144;
  u16* BT1op   = (u16*)(ws + 254804224ull);
  u16* BT1tab  = (u16*)(ws + 254869760ull);
  u16* BT1col  = (u16*)(ws + 254935296ull);
  u16* BT1pr   = (u16*)(ws + 255066368ull);
  float* b1op  = (float*)(ws + 255131904ull);
  float* b1tab = b1op + 512, *b1col = b1op + 1024, *b1pr = b1op + 1536, *b2vec = b1op + 2048;
  int* cnts     = (int*)(ws + 255273216ull);
  int* part     = (int*)(ws + 255273472ull);
  float2* stats = (float2*)(ws + 255277568ull);
  float* cs     = (float*)(ws + 255539712ull);
  float* bb     = (float*)(ws + 255549952ull);
  float* poolp  = (float*)(ws + 255560192ull);      //   2,097,152 : 1024 x 512 partials
  const size_t WS_NEED = 257657344ull;
  if (ws_size < WS_NEED) { probe_k<<<1, 64, 0, stream>>>(out, (float)ws_size); return; }

  // ---- A. full CSR (7 rels), XCD-range-partitioned atomics ----
  (void)hipMemsetAsync(curFul, 0, 3014912ull, stream);
  EdgePtrs ep;
  for (int r = 0; r < 7; ++r) { ep.dst[r] = DST[r]; ep.src[r] = SRC[r]; }
  hist8<<<32768, 256, 0, stream>>>(ep, curFul);
  scan1_k<<<737, 256, 0, stream>>>(curFul, offsFul, part, TOT + 1);
  scan2_k<<<1, 1024, 0, stream>>>(part, 737);
  scan3_k<<<2945, 256, 0, stream>>>(offsFul, curFul, part, TOT + 1);
  fill8<<<32768, 256, 0, stream>>>(ep, curFul, esrcFul);

  // ---- B. weight folding ----
  PackPtrs pp;
  pp.wl2 = Wl2; pp.wr2 = Wr2; pp.g1 = g1;
  pp.bt[0] = BT2_0; pp.bt[1] = BT2_1; pp.bt[2] = BT2_2; pp.bt[3] = BT2_4; pp.bt[4] = BT2rt;
  pack_multi<<<5120, 256, 0, stream>>>(pp);
  csbb_k<<<80, 256, 0, stream>>>(Wl2, Wr2, g1, be1, cs, bb);
  (void)hipMemsetAsync(BT1op, 0, 65536 + 65536 + 131072 + 65536, stream);
  FoldPtrs fp;
  fp.a[0] = W_tab; fp.a[1] = b_tab; fp.a[2] = W_pred; fp.a[3] = b_pred;
  fp.a[4] = W_col; fp.a[5] = b_col; fp.a[6] = W_op;   fp.a[7] = b_op;
  fp.w[0] = Wl1;   fp.w[1] = Wr1;
  fp.bt[0] = BT1op; fp.bt[1] = BT1tab; fp.bt[2] = BT1col; fp.bt[3] = BT1pr;
  fold_multi<<<1256, 256, 0, stream>>>(fp);
  VFPtrs vp;
  vp.bl[0] = bl2; vp.bl[1] = bl1; vp.bl[2] = bl1; vp.bl[3] = bl1; vp.bl[4] = bl1;
  vp.bvec[0] = nullptr; vp.bvec[1] = b_op; vp.bvec[2] = b_tab; vp.bvec[3] = b_col; vp.bvec[4] = b_pred;
  vp.w = Wr1;
  vp.out[0] = b2vec; vp.out[1] = b1op; vp.out[2] = b1tab; vp.out[3] = b1col; vp.out[4] = b1pr;
  vecfold_multi<<<80, 256, 0, stream>>>(vp);

  float* cs0 = cs, *cs1 = cs + 512, *cs2 = cs + 1024, *cs4 = cs + 1536, *csrt = cs + 2048;
  float* bb0 = bb, *bb1 = bb + 512, *bb2 = bb + 1024, *bb4 = bb + 1536, *bbrt = bb + 2048;

  // ---- C. tab (rel0) ----
  (void)hipMemsetAsync(A1, 0, 32768ull * 64 * 2, stream);
  raw_agg<<<1024, 256, 0, stream>>>(offsFul + CSRB[5], esrcFul, x_tab, 2, A1, 64, 0, 2, 32768);
  a1_root<<<256, 256, 0, stream>>>(x_tab, 0, A1, 64, 3, 32768, 1);
  gemm_k<true, 64><<<1024, 256, 0, stream>>>(A1, BT1tab, b1tab, h1);
  ln_stats<<<8192, 256, 0, stream>>>(h1, stats, 32768);
  gemm_t<false><<<1024, 256, 0, stream>>>(h1, BT2_0, hT, stats, cs0, bb0);
  gather_acc<true><<<8192, 256, 0, stream>>>(offsFul + CSRB[0], esrcFul, hT, b2vec, acc, 0, 32768);

  // ---- D. pred (rel1), 2 quarters ----
  (void)hipMemsetAsync(A1, 0, 32768ull * 64 * 2, stream);
  for (int q = 0; q < 2; ++q) {
    int qs = q * 32768;
    raw_agg<<<1024, 256, 0, stream>>>(offsFul + CSRB[3] + qs, esrcFul, x_col, 32, A1, 64, 0, 32, 32768);
    a1_root<<<512, 256, 0, stream>>>(x_pred, qs, A1, 64, 33, 32768, 2);
    gemm_k<true, 64><<<1024, 256, 0, stream>>>(A1, BT1pr, b1pr, h1);
    ln_stats<<<8192, 256, 0, stream>>>(h1, stats, 32768);
    gemm_t<false><<<1024, 256, 0, stream>>>(h1, BT2_1, hT + (size_t)qs * 512, stats, cs1, bb1);
  }
  gather_acc<false><<<8192, 256, 0, stream>>>(offsFul + CSRB[1], esrcFul, hT, nullptr, acc, 0, 65536);

  // ---- E. col (rel2), 2 super-halves x 2 quarters ----
  (void)hipMemsetAsync(A1, 0, 32768ull * 128 * 2, stream);
  for (int hs = 0; hs < 2; ++hs) {
    int S0 = hs * 65536;
    for (int q = 0; q < 2; ++q) {
      int qs = S0 + q * 32768;
      raw_agg<<<1024, 256, 0, stream>>>(offsFul + CSRB[6] + qs, esrcFul, x_col, 32, A1, 128, 0, 32, 32768);
      a1_root<<<4096, 256, 0, stream>>>(x_col, qs, A1, 128, 33, 32768, 5);
      gemm_k<true, 128><<<1024, 256, 0, stream>>>(A1, BT1col, b1col, h1);
      ln_stats<<<8192, 256, 0, stream>>>(h1, stats, 32768);
      gemm_t<false><<<1024, 256, 0, stream>>>(h1, BT2_2, hT + (size_t)q * 32768 * 512, stats, cs2, bb2);
    }
    gather_acc<false><<<8192, 256, 0, stream>>>(offsFul + CSRB[2], esrcFul, hT, nullptr,
                                                acc, S0, S0 + 65536);
  }

  // ---- F. op (rel4 + root), dual transform ----
  (void)hipMemsetAsync(A1, 0, 32768ull * 64 * 2, stream);
  for (int hs = 0; hs < 2; ++hs) {
    int S0 = hs * 65536;
    for (int q = 0; q < 2; ++q) {
      int qs = S0 + q * 32768;
      RawPtrs rp;
      rp.offs = offsFul; rp.esrc = esrcFul; rp.A1 = A1;
      rp.x[0] = x_tab; rp.x[1] = x_pred; rp.x[2] = x_col; rp.x[3] = x_op;
      raw_multi<<<4096, 256, 0, stream>>>(rp, qs);
      a1_root<<<512, 256, 0, stream>>>(x_op, qs, A1, 64, 46, 32768, 2);
      gemm_k<true, 64><<<1024, 256, 0, stream>>>(A1, BT1op, b1op, h1);
      ln_stats<<<8192, 256, 0, stream>>>(h1, stats, 32768);
      gemm_t2<<<2048, 256, 0, stream>>>(h1, BT2rt, BT2_4, acc + (size_t)qs * 512,
                                        hT + (size_t)q * 32768 * 512, stats,
                                        csrt, bbrt, cs4, bb4);
    }
    gather_acc<false><<<8192, 256, 0, stream>>>(offsFul + CSRB[4], esrcFul, hT, nullptr,
                                                acc, S0, S0 + 65536);
  }

  // ---- G. fused ELU + LN2 + pool (no atomics), then output ----
  pool1v<<<1024, 256, 0, stream>>>(acc, batch, NOP, g2, be2, poolp, cnts);
  pool2<<<64, 64, 0, stream>>>(poolp, cnts, Wout, bout, out);
}

// Round 19
// 1454.623 us; speedup vs baseline: 1.0082x; 1.0082x over previous
//
#include <hip/hip_runtime.h>
#include <hip/hip_bf16.h>

typedef unsigned short u16;
typedef __attribute__((ext_vector_type(8))) short bf16x8;
typedef __attribute__((ext_vector_type(4))) short bf16x4;
typedef __attribute__((ext_vector_type(4))) float f32x4;

typedef __attribute__((address_space(1))) const void gv_t;  // global
typedef __attribute__((address_space(3))) void lv_t;        // LDS

#define DEVINL __device__ __forceinline__

DEVINL float bf2f(u16 s) { union { unsigned u; float f; } v; v.u = ((unsigned)s) << 16; return v.f; }
DEVINL u16 f2bf(float f) {
  union { float f; unsigned u; } v; v.f = f;
  return (u16)((v.u + 0x7FFFu + ((v.u >> 16) & 1u)) >> 16);
}
DEVINL float elu_f(float v) { return v > 0.f ? v : __expf(v) - 1.f; }

// ---- ws probe ----
__global__ void probe_k(float* __restrict__ out, float v) { out[threadIdx.x] = v; }

// ---- batched layer-2 packs (g1-scaled): 5 jobs x 1024 blocks ----
struct PackPtrs { const float* wl2; const float* wr2; const float* g1; u16* bt[5]; };
__global__ __launch_bounds__(256) void pack_multi(PackPtrs p) {
  int j = blockIdx.x >> 10;
  int idx = (blockIdx.x & 1023) * 256 + threadIdx.x;
  int k = idx >> 9, n = idx & 511;
  float v;
  if (j < 4) {
    int r = (j == 3) ? 4 : j;
    v = p.wl2[((size_t)r * 512 + k) * 512 + n];
  } else {
    size_t o = (size_t)k * 512 + n;
    v = p.wr2[o] + p.wr2[o + 262144] + p.wr2[o + 524288] + p.wr2[o + 1048576];
  }
  p.bt[j][(size_t)n * 512 + k] = f2bf(v * 0.25f * p.g1[k]);
}

// ---- per-matrix LN-fold constants ----
__global__ __launch_bounds__(256) void csbb_k(const float* __restrict__ wl2,
                                              const float* __restrict__ wr2,
                                              const float* __restrict__ g1,
                                              const float* __restrict__ be1,
                                              float* __restrict__ cs, float* __restrict__ bb) {
  __shared__ float redA[256], redB[256];
  int j = blockIdx.x >> 4;
  int n = (blockIdx.x & 15) * 32 + (threadIdx.x & 31);
  int kg = threadIdx.x >> 5;
  float a = 0.f, b = 0.f;
  for (int k = kg * 64; k < kg * 64 + 64; ++k) {
    float w;
    if (j < 4) {
      int r = (j == 3) ? 4 : j;
      w = wl2[((size_t)r * 512 + k) * 512 + n];
    } else {
      size_t o = (size_t)k * 512 + n;
      w = wr2[o] + wr2[o + 262144] + wr2[o + 524288] + wr2[o + 1048576];
    }
    a += g1[k] * w;
    b += be1[k] * w;
  }
  redA[threadIdx.x] = a;
  redB[threadIdx.x] = b;
  __syncthreads();
  if (kg == 0) {
    float va = 0.f, vb = 0.f;
#pragma unroll
    for (int q = 0; q < 8; ++q) {
      va += redA[(threadIdx.x & 31) + q * 32];
      vb += redB[(threadIdx.x & 31) + q * 32];
    }
    cs[j * 512 + n] = va * 0.25f;
    bb[j * 512 + n] = vb * 0.25f;
  }
}

// ================= batched layer-1 weight folding (18 jobs) =================
struct FoldPtrs { const float* a[8]; const float* w[2]; u16* bt[4]; };
__constant__ int   c_off[19] = {0,16,24,56,64,320,328,360,368,400,416,424,440,696,704,960,1216,1224,1256};
__constant__ int   c_ai[18]  = {0,1,2,3,4,5,6,7,6, 0,1,0, 4,5,4, 4,5,2};
__constant__ int   c_wi[18]  = {0,0,0,0,0,0,0,0,1, 0,0,1, 0,0,1, 0,0,1};
__constant__ int   c_r0[18]  = {0,0,1,1,2,2,4,4,0, 5,5,5, 6,6,6, 3,3,3};
__constant__ float c_sc[18]  = {0.25f,0.25f,0.25f,0.25f,0.25f,0.25f,0.25f,0.25f,0.25f,
                                1.f,1.f,1.f, 1.f,1.f,1.f, 1.f,1.f,1.f};
__constant__ int   c_bt[18]  = {0,0,0,0,0,0,0,0,0, 1,1,1, 2,2,2, 3,3,3};
__constant__ int   c_K[18]   = {64,64,64,64,64,64,64,64,64, 64,64,64, 128,128,128, 64,64,64};
__constant__ int   c_ko[18]  = {0,2,3,7,8,40,41,45,46, 0,2,3, 0,32,33, 0,32,33};

__global__ __launch_bounds__(256) void fold_multi(FoldPtrs p) {
  __shared__ float red[256];
  int b = blockIdx.x;
  int j = 0;
#pragma unroll
  for (int t = 1; t < 18; ++t) j += (b >= c_off[t]);
  int rel = b - c_off[j];
  int f = rel >> 3, nb = rel & 7;
  int tid = threadIdx.x;
  int n = nb * 64 + (tid & 63);
  int kg = tid >> 6;
  const float* A = p.a[c_ai[j]] + (size_t)f * 512;
  const float* W = p.w[c_wi[j]];
  int k0 = kg * 128;
  float acc = 0.f;
  if (j != 8) {
    const float* Wp = W + (size_t)c_r0[j] * 512 * 512 + n;
#pragma unroll 16
    for (int k = k0; k < k0 + 128; ++k) acc += A[k] * Wp[(size_t)k * 512];
  } else {
    const float* W0 = W + n;
    const float* W1 = W + (size_t)262144 + n;
    const float* W2 = W + (size_t)524288 + n;
    const float* W4 = W + (size_t)1048576 + n;
#pragma unroll 8
    for (int k = k0; k < k0 + 128; ++k) {
      size_t o = (size_t)k * 512;
      acc += A[k] * (W0[o] + W1[o] + W2[o] + W4[o]);
    }
  }
  red[tid] = acc;
  __syncthreads();
  if (kg == 0) {
    float v = red[tid] + red[tid + 64] + red[tid + 128] + red[tid + 192];
    p.bt[c_bt[j]][(size_t)n * c_K[j] + c_ko[j] + f] = f2bf(v * c_sc[j]);
  }
}

// ---- batched bias folds ----
struct VFPtrs { const float* bl[5]; const float* bvec[5]; const float* w; float* out[5]; };
__constant__ int   c_vi[5][4] = {{0,1,2,4},{0,1,2,4},{5,-1,-1,-1},{6,-1,-1,-1},{3,-1,-1,-1}};
__constant__ float c_vs[5]    = {0.25f,0.25f,1.f,1.f,1.f};

__global__ __launch_bounds__(256) void vecfold_multi(VFPtrs p) {
  __shared__ float red[256];
  int j = blockIdx.x >> 4, blk = blockIdx.x & 15;
  int tid = threadIdx.x;
  int n = blk * 32 + (tid & 31);
  int kg = tid >> 5;
  const float* bv = p.bvec[j];
  float a = 0.f;
  if (bv) {
    int i1 = c_vi[j][1];
    const float* W0 = p.w + (size_t)c_vi[j][0] * 262144 + n;
    if (i1 < 0) {
#pragma unroll 16
      for (int k = kg * 64; k < kg * 64 + 64; ++k) a += bv[k] * W0[(size_t)k * 512];
    } else {
      const float* W1 = p.w + (size_t)c_vi[j][1] * 262144 + n;
      const float* W2 = p.w + (size_t)c_vi[j][2] * 262144 + n;
      const float* W3 = p.w + (size_t)c_vi[j][3] * 262144 + n;
#pragma unroll 8
      for (int k = kg * 64; k < kg * 64 + 64; ++k) {
        size_t o = (size_t)k * 512;
        a += bv[k] * (W0[o] + W1[o] + W2[o] + W3[o]);
      }
    }
  }
  red[tid] = a;
  __syncthreads();
  if (kg == 0) {
    float v = 0.f;
#pragma unroll
    for (int q = 0; q < 8; ++q) v += red[(tid & 31) + q * 32];
    float bsum = p.bl[j][c_vi[j][0] * 512 + n];
    if (c_vi[j][1] >= 0) {
      bsum += p.bl[j][c_vi[j][1] * 512 + n];
      bsum += p.bl[j][c_vi[j][2] * 512 + n];
      bsum += p.bl[j][c_vi[j][3] * 512 + n];
    }
    p.out[j][n] = (v + bsum) * c_vs[j];
  }
}

// ================= CSR build: XCD-range-partitioned atomics =================
struct EdgePtrs { const int* dst[7]; const int* src[7]; };
__constant__ int c_hoff[8]  = {0,1024,2048,3072,4096,5120,5248,5760};
__constant__ int c_hbase[7] = {0,131072,262144,393216,458752,589824,622592};
__constant__ int c_hne[7]   = {262144,262144,262144,262144,262144,32768,131072};

__global__ __launch_bounds__(256) void hist8(EdgePtrs p, int* __restrict__ cnt) {
  int range = blockIdx.x & 7;
  int lo = range * 94208, hi = lo + 94208;
  for (int chunk = blockIdx.x >> 3; chunk < 5760; chunk += 4096) {
    int j = 0;
#pragma unroll
    for (int t = 1; t < 7; ++t) j += (chunk >= c_hoff[t]);
    int i = (chunk - c_hoff[j]) * 256 + threadIdx.x;
    if (i < c_hne[j]) {
      int idx = c_hbase[j] + p.dst[j][i];
      if (idx >= lo && idx < hi) atomicAdd(&cnt[idx], 1);
    }
  }
}

__global__ __launch_bounds__(256) void fill8(EdgePtrs p, int* __restrict__ cursor,
                                             int* __restrict__ esrc) {
  int range = blockIdx.x & 7;
  int lo = range * 94208, hi = lo + 94208;
  for (int chunk = blockIdx.x >> 3; chunk < 5760; chunk += 4096) {
    int j = 0;
#pragma unroll
    for (int t = 1; t < 7; ++t) j += (chunk >= c_hoff[t]);
    int i = (chunk - c_hoff[j]) * 256 + threadIdx.x;
    if (i < c_hne[j]) {
      int idx = c_hbase[j] + p.dst[j][i];
      if (idx >= lo && idx < hi) {
        int pos = atomicAdd(&cursor[idx], 1);
        esrc[pos] = p.src[j][i];
      }
    }
  }
}

__global__ void scan1_k(const int* __restrict__ in, int* __restrict__ out,
                        int* __restrict__ part, int n) {
  __shared__ int s[256];
  int t = threadIdx.x;
  int base = blockIdx.x * 1024 + t * 4;
  int x0 = 0, x1 = 0, x2 = 0, x3 = 0;
  if (base < n) x0 = in[base];
  if (base + 1 < n) x1 = in[base + 1];
  if (base + 2 < n) x2 = in[base + 2];
  if (base + 3 < n) x3 = in[base + 3];
  int tsum = x0 + x1 + x2 + x3;
  s[t] = tsum;
  __syncthreads();
  for (int off = 1; off < 256; off <<= 1) {
    int v = (t >= off) ? s[t - off] : 0;
    __syncthreads();
    s[t] += v;
    __syncthreads();
  }
  int excl = s[t] - tsum;
  if (base < n) out[base] = excl;
  if (base + 1 < n) out[base + 1] = excl + x0;
  if (base + 2 < n) out[base + 2] = excl + x0 + x1;
  if (base + 3 < n) out[base + 3] = excl + x0 + x1 + x2;
  if (t == 255) part[blockIdx.x] = s[255];
}

__global__ void scan2_k(int* __restrict__ part, int nb) {
  __shared__ int s[1024];
  int t = threadIdx.x;
  int orig = (t < nb) ? part[t] : 0;
  s[t] = orig;
  __syncthreads();
  for (int off = 1; off < 1024; off <<= 1) {
    int v = (t >= off) ? s[t - off] : 0;
    __syncthreads();
    s[t] += v;
    __syncthreads();
  }
  if (t < nb) part[t] = s[t] - orig;
}

__global__ void scan3_k(int* __restrict__ out, int* __restrict__ cursor,
                        const int* __restrict__ part, int n) {
  int i = blockIdx.x * 256 + threadIdx.x;
  if (i < n) {
    int v = out[i] + part[i >> 10];
    out[i] = v;
    cursor[i] = v;
  }
}

// ---- raw-feature segment mean + indicator (8 threads per dst row) ----
__global__ void raw_agg(const int* __restrict__ offs, const int* __restrict__ esrc,
                        const float* __restrict__ x, int F, u16* __restrict__ A1,
                        int K, int colOff, int indCol, int nd) {
  int row = blockIdx.x * 32 + (threadIdx.x >> 3);
  if (row >= nd) return;
  int j = threadIdx.x & 7;
  int e0 = offs[row], e1 = offs[row + 1];
  float acc[4] = {0.f, 0.f, 0.f, 0.f};
  for (int e = e0; e < e1; ++e) {
    int s = esrc[e];
#pragma unroll
    for (int u = 0; u < 4; ++u) {
      int f = j + u * 8;
      if (f < F) acc[u] += x[(size_t)s * F + f];
    }
  }
  float inv = (e1 > e0) ? 1.f / (float)(e1 - e0) : 0.f;
#pragma unroll
  for (int u = 0; u < 4; ++u) {
    int f = j + u * 8;
    if (f < F) A1[(size_t)row * K + colOff + f] = f2bf(acc[u] * inv);
  }
  if (j == 0) A1[(size_t)row * K + indCol] = f2bf((e1 > e0) ? 1.f : 0.f);
}

// batched op-stage: 4 jobs x 1024 blocks, K=64, 32768 rows/chunk
struct RawPtrs { const int* offs; const int* esrc; const float* x[4]; u16* A1; };
__constant__ int c_gF[4]    = {2,4,32,4};
__constant__ int c_gco[4]   = {0,3,8,41};
__constant__ int c_gic[4]   = {2,7,40,45};
__constant__ int c_gcsrb[4] = {0,131072,262144,458752};

__global__ __launch_bounds__(256) void raw_multi(RawPtrs p, int s0) {
  int j = blockIdx.x >> 10;
  int row = (blockIdx.x & 1023) * 32 + (threadIdx.x >> 3);
  int jj = threadIdx.x & 7;
  const int* offs = p.offs + c_gcsrb[j] + s0;
  const float* x = p.x[j];
  int F = c_gF[j];
  int e0 = offs[row], e1 = offs[row + 1];
  float acc[4] = {0.f, 0.f, 0.f, 0.f};
  for (int e = e0; e < e1; ++e) {
    int s = p.esrc[e];
#pragma unroll
    for (int u = 0; u < 4; ++u) {
      int f = jj + u * 8;
      if (f < F) acc[u] += x[(size_t)s * F + f];
    }
  }
  float inv = (e1 > e0) ? 1.f / (float)(e1 - e0) : 0.f;
#pragma unroll
  for (int u = 0; u < 4; ++u) {
    int f = jj + u * 8;
    if (f < F) p.A1[(size_t)row * 64 + c_gco[j] + f] = f2bf(acc[u] * inv);
  }
  if (jj == 0) p.A1[(size_t)row * 64 + c_gic[j]] = f2bf((e1 > e0) ? 1.f : 0.f);
}

// ---- copy root raw features into A1 ----
__global__ void a1_root(const float* __restrict__ x, int rowBase, u16* __restrict__ A1,
                        int K, int rootOff, int nd, int lf) {
  int idx = blockIdx.x * 256 + threadIdx.x;
  int i = idx >> lf, f = idx & ((1 << lf) - 1);
  if (i >= nd) return;
  A1[(size_t)i * K + rootOff + f] = f2bf(x[(((size_t)(rowBase + i)) << lf) + f]);
}

// ---- fused gather + acc RMW: 2 dst rows per wave ----
template <bool FIRST>
__global__ __launch_bounds__(256) void gather_acc(
    const int* __restrict__ offs, const int* __restrict__ esrc,
    const u16* __restrict__ hT, const float* __restrict__ bias,
    u16* __restrict__ acc, int s0, int s1) {
  int w0 = (blockIdx.x * 4 + (threadIdx.x >> 6)) * 2;
  int l = threadIdx.x & 63;
  int eA0 = offs[w0], eB0 = offs[w0 + 1], eB1 = offs[w0 + 2];
  int lenA = eB0 - eA0, lenB = eB1 - eB0;
  int maxLen = lenA > lenB ? lenA : lenB;
  float sumA[8] = {0.f, 0.f, 0.f, 0.f, 0.f, 0.f, 0.f, 0.f};
  float sumB[8] = {0.f, 0.f, 0.f, 0.f, 0.f, 0.f, 0.f, 0.f};
  bool fA = false, fB = false;
  for (int i = 0; i < maxLen; ++i) {
    int sa = (i < lenA) ? esrc[eA0 + i] : -1;
    int sb = (i < lenB) ? esrc[eB0 + i] : -1;
    bool da = (sa >= s0 && sa < s1);
    bool db = (sb >= s0 && sb < s1);
    bf16x8 va, vb;
    if (da) va = *(const bf16x8*)&hT[(size_t)(sa - s0) * 512 + l * 8];
    if (db) vb = *(const bf16x8*)&hT[(size_t)(sb - s0) * 512 + l * 8];
    if (da) {
      fA = true;
#pragma unroll
      for (int j = 0; j < 8; ++j) sumA[j] += bf2f((u16)va[j]);
    }
    if (db) {
      fB = true;
#pragma unroll
      for (int j = 0; j < 8; ++j) sumB[j] += bf2f((u16)vb[j]);
    }
  }
  float invA = (lenA > 0) ? 1.f / (float)lenA : 0.f;
  float invB = (lenB > 0) ? 1.f / (float)lenB : 0.f;
  u16* apA = acc + (size_t)w0 * 512 + l * 8;
  u16* apB = apA + 512;
  bf16x8 r;
  if (FIRST) {
#pragma unroll
    for (int j = 0; j < 8; ++j) r[j] = (short)f2bf(bias[l * 8 + j] + sumA[j] * invA);
    *(bf16x8*)apA = r;
#pragma unroll
    for (int j = 0; j < 8; ++j) r[j] = (short)f2bf(bias[l * 8 + j] + sumB[j] * invB);
    *(bf16x8*)apB = r;
  } else {
    if (fA) {
      bf16x8 old = *(const bf16x8*)apA;
#pragma unroll
      for (int j = 0; j < 8; ++j) r[j] = (short)f2bf(bf2f((u16)old[j]) + sumA[j] * invA);
      *(bf16x8*)apA = r;
    }
    if (fB) {
      bf16x8 old = *(const bf16x8*)apB;
#pragma unroll
      for (int j = 0; j < 8; ++j) r[j] = (short)f2bf(bf2f((u16)old[j]) + sumB[j] * invB);
      *(bf16x8*)apB = r;
    }
  }
}

// ---- MFMA GEMM (layer-1, K=64/128, M=32768): XCD-swizzled flat grid 1024 ----
template <bool ELU, int K>
__global__ __launch_bounds__(256) void gemm_k(
    const u16* __restrict__ A, const u16* __restrict__ BT,
    const float* __restrict__ bias, u16* __restrict__ C) {
  __shared__ u16 As[128 * 64];
  __shared__ u16 Bs[128 * 64];
  int b = blockIdx.x;
  int u = (b & 7) * 128 + (b >> 3);
  int bm = (u >> 2) * 128;
  int bn = (u & 3) * 128;
  int tid = threadIdx.x;
  int wid = tid >> 6, lane = tid & 63;
  int wm = wid >> 1, wn = wid & 1;
  int r16 = lane & 15, hi4 = lane >> 4;
  int srow = tid >> 3;
  int scol = ((tid & 7) ^ (srow & 7)) * 8;
  int sw = r16 & 7;
  f32x4 acc[4][4];
#pragma unroll
  for (int i = 0; i < 4; ++i)
#pragma unroll
    for (int j = 0; j < 4; ++j) acc[i][j] = (f32x4){0.f, 0.f, 0.f, 0.f};

#pragma unroll
  for (int k0 = 0; k0 < K; k0 += 64) {
    __syncthreads();
#pragma unroll
    for (int i = 0; i < 4; ++i) {
      const u16* ga = A + (size_t)(bm + i * 32 + srow) * K + k0 + scol;
      const u16* gb = BT + (size_t)(bn + i * 32 + srow) * K + k0 + scol;
      __builtin_amdgcn_global_load_lds((gv_t*)ga, (lv_t*)(As + i * 2048 + wid * 512), 16, 0, 0);
      __builtin_amdgcn_global_load_lds((gv_t*)gb, (lv_t*)(Bs + i * 2048 + wid * 512), 16, 0, 0);
    }
    __syncthreads();
#pragma unroll
    for (int kk = 0; kk < 64; kk += 32) {
      bf16x8 af[4], bfr[4];
#pragma unroll
      for (int f = 0; f < 4; ++f) {
        int grp = (kk >> 3) + hi4;
        af[f]  = *(const bf16x8*)&As[(wm * 64 + f * 16 + r16) * 64 + ((grp ^ sw) << 3)];
        bfr[f] = *(const bf16x8*)&Bs[(wn * 64 + f * 16 + r16) * 64 + ((grp ^ sw) << 3)];
      }
#pragma unroll
      for (int mf = 0; mf < 4; ++mf)
#pragma unroll
        for (int nf = 0; nf < 4; ++nf)
          acc[mf][nf] = __builtin_amdgcn_mfma_f32_16x16x32_bf16(bfr[nf], af[mf], acc[mf][nf], 0, 0, 0);
    }
  }
#pragma unroll
  for (int mf = 0; mf < 4; ++mf) {
    int r = bm + wm * 64 + mf * 16 + r16;
#pragma unroll
    for (int nf = 0; nf < 4; ++nf) {
      int c0 = bn + wn * 64 + nf * 16 + hi4 * 4;
      u16* cp = C + (size_t)r * 512 + c0;
      f32x4 bv = *(const f32x4*)&bias[c0];
      bf16x4 res;
#pragma unroll
      for (int j = 0; j < 4; ++j) {
        float v = acc[mf][nf][j] + bv[j];
        if (ELU) v = elu_f(v);
        res[j] = (short)f2bf(v);
      }
      *(bf16x4*)cp = res;
    }
  }
}

// ---- per-row LN stats of h1 (wave per row) ----
__global__ void ln_stats(const u16* __restrict__ H, float2* __restrict__ stats, int rows) {
  int w = blockIdx.x * 4 + (threadIdx.x >> 6);
  if (w >= rows) return;
  int l = threadIdx.x & 63;
  bf16x8 v = *(const bf16x8*)&H[(size_t)w * 512 + l * 8];
  float x[8];
  float s = 0.f;
#pragma unroll
  for (int j = 0; j < 8; ++j) { x[j] = bf2f((u16)v[j]); s += x[j]; }
#pragma unroll
  for (int m = 1; m < 64; m <<= 1) s += __shfl_xor(s, m, 64);
  float mean = s * (1.f / 512.f);
  float q = 0.f;
#pragma unroll
  for (int j = 0; j < 8; ++j) { float d = x[j] - mean; q += d * d; }
#pragma unroll
  for (int m = 1; m < 64; m <<= 1) q += __shfl_xor(q, m, 64);
  if (l == 0) stats[w] = make_float2(mean, rsqrtf(q * (1.f / 512.f) + 1e-5f));
}

// ---- transform GEMM (K=512) with fused LN-of-A; XCD-chunked swizzle ----
template <bool ACC>
__global__ __launch_bounds__(256) void gemm_t(
    const u16* __restrict__ A, const u16* __restrict__ BT, u16* __restrict__ C,
    const float2* __restrict__ stats, const float* __restrict__ cs,
    const float* __restrict__ bb) {
  __shared__ u16 As[128 * 64];
  __shared__ u16 Bs[128 * 64];
  int b = blockIdx.x;
  int u = (b & 7) * 128 + (b >> 3);
  int bm = (u >> 2) * 128;
  int bn = (u & 3) * 128;
  int tid = threadIdx.x;
  int wid = tid >> 6, lane = tid & 63;
  int wm = wid >> 1, wn = wid & 1;
  int r16 = lane & 15, hi4 = lane >> 4;
  int srow = tid >> 3;
  int scol = ((tid & 7) ^ (srow & 7)) * 8;
  int sw = r16 & 7;
  f32x4 acc[4][4];
#pragma unroll
  for (int i = 0; i < 4; ++i)
#pragma unroll
    for (int j = 0; j < 4; ++j) acc[i][j] = (f32x4){0.f, 0.f, 0.f, 0.f};

#pragma unroll
  for (int k0 = 0; k0 < 512; k0 += 64) {
    __syncthreads();
#pragma unroll
    for (int i = 0; i < 4; ++i) {
      const u16* ga = A + (size_t)(bm + i * 32 + srow) * 512 + k0 + scol;
      const u16* gb = BT + (size_t)(bn + i * 32 + srow) * 512 + k0 + scol;
      __builtin_amdgcn_global_load_lds((gv_t*)ga, (lv_t*)(As + i * 2048 + wid * 512), 16, 0, 0);
      __builtin_amdgcn_global_load_lds((gv_t*)gb, (lv_t*)(Bs + i * 2048 + wid * 512), 16, 0, 0);
    }
    __syncthreads();
#pragma unroll
    for (int kk = 0; kk < 64; kk += 32) {
      bf16x8 af[4], bfr[4];
#pragma unroll
      for (int f = 0; f < 4; ++f) {
        int grp = (kk >> 3) + hi4;
        af[f]  = *(const bf16x8*)&As[(wm * 64 + f * 16 + r16) * 64 + ((grp ^ sw) << 3)];
        bfr[f] = *(const bf16x8*)&Bs[(wn * 64 + f * 16 + r16) * 64 + ((grp ^ sw) << 3)];
      }
#pragma unroll
      for (int mf = 0; mf < 4; ++mf)
#pragma unroll
        for (int nf = 0; nf < 4; ++nf)
          acc[mf][nf] = __builtin_amdgcn_mfma_f32_16x16x32_bf16(bfr[nf], af[mf], acc[mf][nf], 0, 0, 0);
    }
  }
#pragma unroll
  for (int mf = 0; mf < 4; ++mf) {
    int r = bm + wm * 64 + mf * 16 + r16;
    float2 st = stats[r];
    float mr = st.x * st.y;
#pragma unroll
    for (int nf = 0; nf < 4; ++nf) {
      int c0 = bn + wn * 64 + nf * 16 + hi4 * 4;
      u16* cp = C + (size_t)r * 512 + c0;
      f32x4 csv = *(const f32x4*)&cs[c0];
      f32x4 bbv = *(const f32x4*)&bb[c0];
      bf16x4 res;
      if (ACC) {
        bf16x4 oldv = *(const bf16x4*)cp;
#pragma unroll
        for (int j = 0; j < 4; ++j) {
          float v = st.y * acc[mf][nf][j] - mr * csv[j] + bbv[j] + bf2f((u16)oldv[j]);
          res[j] = (short)f2bf(v);
        }
      } else {
#pragma unroll
        for (int j = 0; j < 4; ++j) {
          float v = st.y * acc[mf][nf][j] - mr * csv[j] + bbv[j];
          res[j] = (short)f2bf(v);
        }
      }
      *(bf16x4*)cp = res;
    }
  }
}

// ---- dual transform for stage F ----
__global__ __launch_bounds__(256) void gemm_t2(
    const u16* __restrict__ A, const u16* __restrict__ BTrt, const u16* __restrict__ BT4,
    u16* __restrict__ Cacc, u16* __restrict__ ChT, const float2* __restrict__ stats,
    const float* __restrict__ csrt, const float* __restrict__ bbrt,
    const float* __restrict__ cs4, const float* __restrict__ bb4) {
  __shared__ u16 As[128 * 64];
  __shared__ u16 Bs[128 * 64];
  bool second = blockIdx.x >= 1024;
  const u16* BT = second ? BT4 : BTrt;
  u16* C = second ? ChT : Cacc;
  const float* cs = second ? cs4 : csrt;
  const float* bb = second ? bb4 : bbrt;
  int b = blockIdx.x & 1023;
  int u = (b & 7) * 128 + (b >> 3);
  int bm = (u >> 2) * 128;
  int bn = (u & 3) * 128;
  int tid = threadIdx.x;
  int wid = tid >> 6, lane = tid & 63;
  int wm = wid >> 1, wn = wid & 1;
  int r16 = lane & 15, hi4 = lane >> 4;
  int srow = tid >> 3;
  int scol = ((tid & 7) ^ (srow & 7)) * 8;
  int sw = r16 & 7;
  f32x4 acc[4][4];
#pragma unroll
  for (int i = 0; i < 4; ++i)
#pragma unroll
    for (int j = 0; j < 4; ++j) acc[i][j] = (f32x4){0.f, 0.f, 0.f, 0.f};

#pragma unroll
  for (int k0 = 0; k0 < 512; k0 += 64) {
    __syncthreads();
#pragma unroll
    for (int i = 0; i < 4; ++i) {
      const u16* ga = A + (size_t)(bm + i * 32 + srow) * 512 + k0 + scol;
      const u16* gb = BT + (size_t)(bn + i * 32 + srow) * 512 + k0 + scol;
      __builtin_amdgcn_global_load_lds((gv_t*)ga, (lv_t*)(As + i * 2048 + wid * 512), 16, 0, 0);
      __builtin_amdgcn_global_load_lds((gv_t*)gb, (lv_t*)(Bs + i * 2048 + wid * 512), 16, 0, 0);
    }
    __syncthreads();
#pragma unroll
    for (int kk = 0; kk < 64; kk += 32) {
      bf16x8 af[4], bfr[4];
#pragma unroll
      for (int f = 0; f < 4; ++f) {
        int grp = (kk >> 3) + hi4;
        af[f]  = *(const bf16x8*)&As[(wm * 64 + f * 16 + r16) * 64 + ((grp ^ sw) << 3)];
        bfr[f] = *(const bf16x8*)&Bs[(wn * 64 + f * 16 + r16) * 64 + ((grp ^ sw) << 3)];
      }
#pragma unroll
      for (int mf = 0; mf < 4; ++mf)
#pragma unroll
        for (int nf = 0; nf < 4; ++nf)
          acc[mf][nf] = __builtin_amdgcn_mfma_f32_16x16x32_bf16(bfr[nf], af[mf], acc[mf][nf], 0, 0, 0);
    }
  }
#pragma unroll
  for (int mf = 0; mf < 4; ++mf) {
    int r = bm + wm * 64 + mf * 16 + r16;
    float2 st = stats[r];
    float mr = st.x * st.y;
#pragma unroll
    for (int nf = 0; nf < 4; ++nf) {
      int c0 = bn + wn * 64 + nf * 16 + hi4 * 4;
      u16* cp = C + (size_t)r * 512 + c0;
      f32x4 csv = *(const f32x4*)&cs[c0];
      f32x4 bbv = *(const f32x4*)&bb[c0];
      bf16x4 res;
      if (!second) {
        bf16x4 oldv = *(const bf16x4*)cp;
#pragma unroll
        for (int j = 0; j < 4; ++j) {
          float v = st.y * acc[mf][nf][j] - mr * csv[j] + bbv[j] + bf2f((u16)oldv[j]);
          res[j] = (short)f2bf(v);
        }
      } else {
#pragma unroll
        for (int j = 0; j < 4; ++j) {
          float v = st.y * acc[mf][nf][j] - mr * csv[j] + bbv[j];
          res[j] = (short)f2bf(v);
        }
      }
      *(bf16x4*)cp = res;
    }
  }
}

// ---- fused ELU + LN2 + pool partial (16 parts/graph, NO atomics) ----
DEVINL int lowb(const int* a, int n, int v) {
  int lo = 0, hi = n;
  while (lo < hi) { int m = (lo + hi) >> 1; if (a[m] < v) lo = m + 1; else hi = m; }
  return lo;
}

__global__ __launch_bounds__(256) void pool1v(const u16* __restrict__ H,
                                              const int* __restrict__ batch, int nOp,
                                              const float* __restrict__ g2,
                                              const float* __restrict__ be2,
                                              float* __restrict__ poolp,
                                              int* __restrict__ cnts) {
  __shared__ float red[4][512];
  int gr = blockIdx.x >> 4, part = blockIdx.x & 15;
  int lo = lowb(batch, nOp, gr), hi = lowb(batch, nOp, gr + 1);
  if (part == 0 && threadIdx.x == 0) cnts[gr] = hi - lo;
  int len = hi - lo;
  int chunk = (len + 15) >> 4;
  int r0 = lo + part * chunk;
  int r1 = r0 + chunk;
  if (r1 > hi) r1 = hi;
  int wv = threadIdx.x >> 6, l = threadIdx.x & 63;
  float a[8] = {0.f, 0.f, 0.f, 0.f, 0.f, 0.f, 0.f, 0.f};
  float gv[8], bv[8];
#pragma unroll
  for (int j = 0; j < 8; ++j) { gv[j] = g2[l * 8 + j]; bv[j] = be2[l * 8 + j]; }
  for (int r = r0 + wv; r < r1; r += 4) {
    bf16x8 v = *(const bf16x8*)&H[(size_t)r * 512 + l * 8];
    float x[8];
    float s = 0.f;
#pragma unroll
    for (int j = 0; j < 8; ++j) {
      x[j] = elu_f(bf2f((u16)v[j]));
      s += x[j];
    }
#pragma unroll
    for (int m = 1; m < 64; m <<= 1) s += __shfl_xor(s, m, 64);
    float mean = s * (1.f / 512.f);
    float q = 0.f;
#pragma unroll
    for (int j = 0; j < 8; ++j) { float d = x[j] - mean; q += d * d; }
#pragma unroll
    for (int m = 1; m < 64; m <<= 1) q += __shfl_xor(q, m, 64);
    float rsd = rsqrtf(q * (1.f / 512.f) + 1e-5f);
#pragma unroll
    for (int j = 0; j < 8; ++j) a[j] += (x[j] - mean) * rsd * gv[j] + bv[j];
  }
#pragma unroll
  for (int j = 0; j < 8; ++j) red[wv][l * 8 + j] = a[j];
  __syncthreads();
  if (wv == 0) {
    float* dst = poolp + (size_t)blockIdx.x * 512;
#pragma unroll
    for (int j = 0; j < 8; ++j) {
      int c = l * 8 + j;
      dst[c] = red[0][c] + red[1][c] + red[2][c] + red[3][c];
    }
  }
}

__global__ void pool2(const float* __restrict__ poolp, const int* __restrict__ cnts,
                      const float* __restrict__ Wout, const float* __restrict__ bout,
                      float* __restrict__ out) {
  int gg = blockIdx.x;
  int l = threadIdx.x;
  float s = 0.f;
#pragma unroll
  for (int j = 0; j < 8; ++j) {
    int c = l * 8 + j;
    float t = 0.f;
#pragma unroll
    for (int p = 0; p < 16; ++p) t += poolp[(size_t)(gg * 16 + p) * 512 + c];
    s += t * Wout[c];
  }
#pragma unroll
  for (int m = 1; m < 64; m <<= 1) s += __shfl_xor(s, m, 64);
  if (l == 0) {
    int c = cnts[gg];
    if (c < 1) c = 1;
    out[gg] = s / (float)c + bout[0];
  }
}

extern "C" void kernel_launch(void* const* d_in, const int* in_sizes, int n_in,
                              void* d_out, int out_size, void* d_ws, size_t ws_size,
                              hipStream_t stream) {
  (void)in_sizes; (void)n_in; (void)out_size;
  const float* x_op   = (const float*)d_in[0];
  const float* x_tab  = (const float*)d_in[1];
  const float* x_col  = (const float*)d_in[2];
  const float* x_pred = (const float*)d_in[3];
  const float* W_op = (const float*)d_in[4],  *b_op = (const float*)d_in[5];
  const float* W_tab = (const float*)d_in[6], *b_tab = (const float*)d_in[7];
  const float* W_col = (const float*)d_in[8], *b_col = (const float*)d_in[9];
  const float* W_pred = (const float*)d_in[10], *b_pred = (const float*)d_in[11];
  const float* Wl1 = (const float*)d_in[12];
  const float* bl1 = (const float*)d_in[13];
  const float* Wr1 = (const float*)d_in[14];
  const float* Wl2 = (const float*)d_in[15];
  const float* bl2 = (const float*)d_in[16];
  const float* Wr2 = (const float*)d_in[17];
  const float* g1  = (const float*)d_in[18];
  const float* be1 = (const float*)d_in[19];
  const float* g2  = (const float*)d_in[20];
  const float* be2 = (const float*)d_in[21];
  const float* Wout = (const float*)d_in[22];
  const float* bout = (const float*)d_in[23];
  const int* SRC[7], *DST[7];
  for (int r = 0; r < 7; ++r) { SRC[r] = (const int*)d_in[24 + 2 * r]; DST[r] = (const int*)d_in[25 + 2 * r]; }
  const int* batch = (const int*)d_in[38];
  float* out = (float*)d_out;

  const int CSRB[7] = {0, 131072, 262144, 393216, 458752, 589824, 622592};
  const int TOT = 753664;
  const int NOP = 131072;

  // ---- workspace layout ----
  char* ws = (char*)d_ws;
  u16* acc     = (u16*)ws;                          // 134,217,728
  u16* h1      = (u16*)(ws + 134217728ull);         //  33,554,432
  int* curFul  = (int*)(ws + 134217728ull);         //   (overlay)
  u16* hT      = (u16*)(ws + 167772160ull);         //  67,108,864
  u16* A1      = (u16*)(ws + 234881024ull);         //   8,388,608
  int* offsFul = (int*)(ws + 243269632ull);         //   3,014,912
  int* esrcFul = (int*)(ws + 246284544ull);         //   5,898,240
  u16* BT2_0   = (u16*)(ws + 252182784ull);         //   5 x 524,288
  u16* BT2_1   = BT2_0 + 262144;
  u16* BT2_2   = BT2_1 + 262144;
  u16* BT2_4   = BT2_2 + 262144;
  u16* BT2rt   = BT2_4 + 262144;
  u16* BT1op   = (u16*)(ws + 254804224ull);
  u16* BT1tab  = (u16*)(ws + 254869760ull);
  u16* BT1col  = (u16*)(ws + 254935296ull);
  u16* BT1pr   = (u16*)(ws + 255066368ull);
  float* b1op  = (float*)(ws + 255131904ull);
  float* b1tab = b1op + 512, *b1col = b1op + 1024, *b1pr = b1op + 1536, *b2vec = b1op + 2048;
  int* cnts     = (int*)(ws + 255273216ull);
  int* part     = (int*)(ws + 255273472ull);
  float2* stats = (float2*)(ws + 255277568ull);
  float* cs     = (float*)(ws + 255539712ull);
  float* bb     = (float*)(ws + 255549952ull);
  float* poolp  = (float*)(ws + 255560192ull);      //   2,097,152 : 1024 x 512 partials
  const size_t WS_NEED = 257657344ull;
  if (ws_size < WS_NEED) { probe_k<<<1, 64, 0, stream>>>(out, (float)ws_size); return; }

  // ---- A. full CSR (7 rels), XCD-range-partitioned atomics ----
  (void)hipMemsetAsync(curFul, 0, 3014912ull, stream);
  EdgePtrs ep;
  for (int r = 0; r < 7; ++r) { ep.dst[r] = DST[r]; ep.src[r] = SRC[r]; }
  hist8<<<32768, 256, 0, stream>>>(ep, curFul);
  scan1_k<<<737, 256, 0, stream>>>(curFul, offsFul, part, TOT + 1);
  scan2_k<<<1, 1024, 0, stream>>>(part, 737);
  scan3_k<<<2945, 256, 0, stream>>>(offsFul, curFul, part, TOT + 1);
  fill8<<<32768, 256, 0, stream>>>(ep, curFul, esrcFul);

  // ---- B. weight folding ----
  PackPtrs pp;
  pp.wl2 = Wl2; pp.wr2 = Wr2; pp.g1 = g1;
  pp.bt[0] = BT2_0; pp.bt[1] = BT2_1; pp.bt[2] = BT2_2; pp.bt[3] = BT2_4; pp.bt[4] = BT2rt;
  pack_multi<<<5120, 256, 0, stream>>>(pp);
  csbb_k<<<80, 256, 0, stream>>>(Wl2, Wr2, g1, be1, cs, bb);
  (void)hipMemsetAsync(BT1op, 0, 65536 + 65536 + 131072 + 65536, stream);
  FoldPtrs fp;
  fp.a[0] = W_tab; fp.a[1] = b_tab; fp.a[2] = W_pred; fp.a[3] = b_pred;
  fp.a[4] = W_col; fp.a[5] = b_col; fp.a[6] = W_op;   fp.a[7] = b_op;
  fp.w[0] = Wl1;   fp.w[1] = Wr1;
  fp.bt[0] = BT1op; fp.bt[1] = BT1tab; fp.bt[2] = BT1col; fp.bt[3] = BT1pr;
  fold_multi<<<1256, 256, 0, stream>>>(fp);
  VFPtrs vp;
  vp.bl[0] = bl2; vp.bl[1] = bl1; vp.bl[2] = bl1; vp.bl[3] = bl1; vp.bl[4] = bl1;
  vp.bvec[0] = nullptr; vp.bvec[1] = b_op; vp.bvec[2] = b_tab; vp.bvec[3] = b_col; vp.bvec[4] = b_pred;
  vp.w = Wr1;
  vp.out[0] = b2vec; vp.out[1] = b1op; vp.out[2] = b1tab; vp.out[3] = b1col; vp.out[4] = b1pr;
  vecfold_multi<<<80, 256, 0, stream>>>(vp);

  float* cs0 = cs, *cs1 = cs + 512, *cs2 = cs + 1024, *cs4 = cs + 1536, *csrt = cs + 2048;
  float* bb0 = bb, *bb1 = bb + 512, *bb2 = bb + 1024, *bb4 = bb + 1536, *bbrt = bb + 2048;

  // ---- C. tab (rel0) ----
  (void)hipMemsetAsync(A1, 0, 32768ull * 64 * 2, stream);
  raw_agg<<<1024, 256, 0, stream>>>(offsFul + CSRB[5], esrcFul, x_tab, 2, A1, 64, 0, 2, 32768);
  a1_root<<<256, 256, 0, stream>>>(x_tab, 0, A1, 64, 3, 32768, 1);
  gemm_k<true, 64><<<1024, 256, 0, stream>>>(A1, BT1tab, b1tab, h1);
  ln_stats<<<8192, 256, 0, stream>>>(h1, stats, 32768);
  gemm_t<false><<<1024, 256, 0, stream>>>(h1, BT2_0, hT, stats, cs0, bb0);
  gather_acc<true><<<16384, 256, 0, stream>>>(offsFul + CSRB[0], esrcFul, hT, b2vec, acc, 0, 32768);

  // ---- D. pred (rel1), 2 quarters ----
  (void)hipMemsetAsync(A1, 0, 32768ull * 64 * 2, stream);
  for (int q = 0; q < 2; ++q) {
    int qs = q * 32768;
    raw_agg<<<1024, 256, 0, stream>>>(offsFul + CSRB[3] + qs, esrcFul, x_col, 32, A1, 64, 0, 32, 32768);
    a1_root<<<512, 256, 0, stream>>>(x_pred, qs, A1, 64, 33, 32768, 2);
    gemm_k<true, 64><<<1024, 256, 0, stream>>>(A1, BT1pr, b1pr, h1);
    ln_stats<<<8192, 256, 0, stream>>>(h1, stats, 32768);
    gemm_t<false><<<1024, 256, 0, stream>>>(h1, BT2_1, hT + (size_t)qs * 512, stats, cs1, bb1);
  }
  gather_acc<false><<<16384, 256, 0, stream>>>(offsFul + CSRB[1], esrcFul, hT, nullptr, acc, 0, 65536);

  // ---- E. col (rel2), 2 super-halves x 2 quarters ----
  (void)hipMemsetAsync(A1, 0, 32768ull * 128 * 2, stream);
  for (int hs = 0; hs < 2; ++hs) {
    int S0 = hs * 65536;
    for (int q = 0; q < 2; ++q) {
      int qs = S0 + q * 32768;
      raw_agg<<<1024, 256, 0, stream>>>(offsFul + CSRB[6] + qs, esrcFul, x_col, 32, A1, 128, 0, 32, 32768);
      a1_root<<<4096, 256, 0, stream>>>(x_col, qs, A1, 128, 33, 32768, 5);
      gemm_k<true, 128><<<1024, 256, 0, stream>>>(A1, BT1col, b1col, h1);
      ln_stats<<<8192, 256, 0, stream>>>(h1, stats, 32768);
      gemm_t<false><<<1024, 256, 0, stream>>>(h1, BT2_2, hT + (size_t)q * 32768 * 512, stats, cs2, bb2);
    }
    gather_acc<false><<<16384, 256, 0, stream>>>(offsFul + CSRB[2], esrcFul, hT, nullptr,
                                                 acc, S0, S0 + 65536);
  }

  // ---- F. op (rel4 + root), dual transform ----
  (void)hipMemsetAsync(A1, 0, 32768ull * 64 * 2, stream);
  for (int hs = 0; hs < 2; ++hs) {
    int S0 = hs * 65536;
    for (int q = 0; q < 2; ++q) {
      int qs = S0 + q * 32768;
      RawPtrs rp;
      rp.offs = offsFul; rp.esrc = esrcFul; rp.A1 = A1;
      rp.x[0] = x_tab; rp.x[1] = x_pred; rp.x[2] = x_col; rp.x[3] = x_op;
      raw_multi<<<4096, 256, 0, stream>>>(rp, qs);
      a1_root<<<512, 256, 0, stream>>>(x_op, qs, A1, 64, 46, 32768, 2);
      gemm_k<true, 64><<<1024, 256, 0, stream>>>(A1, BT1op, b1op, h1);
      ln_stats<<<8192, 256, 0, stream>>>(h1, stats, 32768);
      gemm_t2<<<2048, 256, 0, stream>>>(h1, BT2rt, BT2_4, acc + (size_t)qs * 512,
                                        hT + (size_t)q * 32768 * 512, stats,
                                        csrt, bbrt, cs4, bb4);
    }
    gather_acc<false><<<16384, 256, 0, stream>>>(offsFul + CSRB[4], esrcFul, hT, nullptr,
                                                 acc, S0, S0 + 65536);
  }

  // ---- G. fused ELU + LN2 + pool (no atomics), then output ----
  pool1v<<<1024, 256, 0, stream>>>(acc, batch, NOP, g2, be2, poolp, cnts);
  pool2<<<64, 64, 0, stream>>>(poolp, cnts, Wout, bout, out);
}